// Round 15
// baseline (290.551 us; speedup 1.0000x reference)
//
#include <hip/hip_runtime.h>
#include <hip/hip_fp16.h>

// Tree NN: reps = emb[tokens] (4096 x 128 x 128); 7x: reps = tanh(concat(pairs) @ W_tree^T + b);
// out = root @ W_cls^T + b_cls.
//
// R15: cut LDS-read INSTRUCTIONS (R14 showed ds_read cost is per-instruction, not per-byte:
// clamping conflicts away was neutral). R13 audit: 160 ds_read_b128/wave/pair x 12 waves/CU
// x 12 cyc ~ 90% LDS-issue busy = the binding pipe. Change: each wave owns 64 features
// (Wf[4][8] = 128 VGPR); L0/L1 m-tiles split across wave-halves (mhalf = wid>>1); deep
// levels (1 m-tile) split by n: wave w computes its 2 deep n-tiles d0=(wid>>1)*2 from its
// own Wf slice. Reads/wave/pair 160 -> 112; block total 640 -> 448 (L0+L1 halve).
// VGPR ~190 -> launch_bounds(256,1) (cap 512/2=256; R1 precedent 184 no-spill);
// 2 blocks/CU (VGPR-bound), LDS 106 KB <= 160. Grid 512.
// Tripwire: VGPR <= 128 or WRITE_SIZE in MBs = spill -> revert to R13.
//
// Flow per pair (unchanged from R13): s-gather -> L0 A->B, L1 B->A, L2 A->B, L3 B->A,
// L4 A->bufC (per sample); batched L5 bufC->A, L6+classifier. Token preload one section
// early; conflict-reduced gather writes. fp16 MFMA 16x16x32 (K-split in deep levels),
// fp32 accumulate/tanh/classifier.

typedef _Float16 half8 __attribute__((ext_vector_type(8)));
typedef float floatx4 __attribute__((ext_vector_type(4)));

#define STRIDE 264   // 256 + 8 fp16 pad: A-row ds_read_b128 conflict-free
#define UROW   33    // uint4 per row
#define NPAIR  2048

__device__ __forceinline__ float fast_tanh(float x) {
  // No clamp needed: e=inf -> 1; e=0 -> -1. Inputs never NaN.
  float e = __expf(2.f * x);
  return 1.f - 2.f * __builtin_amdgcn_rcpf(e + 1.f);
}

__device__ __forceinline__ unsigned pkrtz(float a, float b) {
  auto h = __builtin_amdgcn_cvt_pkrtz(a, b);   // __fp16 ext_vector(2)
  return __builtin_bit_cast(unsigned, h);
}

// Gather: thread (row=t&63, seg=t>>6) covers leaf 2*row+(seg>>1), feature-half seg&1.
__device__ __forceinline__ void gather_leafhalf(int tok, const float* __restrict__ emb,
                                                _Float16* buf, int row, int seg) {
  const float4* src = (const float4*)emb + (size_t)tok * 32 + (seg & 1) * 16;
  uint4* dst = (uint4*)buf + row * UROW + seg * 8;
#pragma unroll
  for (int j = 0; j < 8; ++j) {
    float4 x = src[2 * j], y = src[2 * j + 1];
    uint4 w;
    w.x = pkrtz(x.x, x.y); w.y = pkrtz(x.z, x.w);
    w.z = pkrtz(y.x, y.y); w.w = pkrtz(y.z, y.w);
    dst[j] = w;
  }
}

// Full-width level section for this wave: MTW m-tiles starting at m0, 4 n-tiles (wave's
// 64 features). One A-read feeds 4 MFMAs. A-frag A[m=lane&15][k=quad*8+j];
// B[k][n=lane&15]; D col=lane&15, row=quad*4+reg (verified, learn_hip m89/m91).
template<int MTW, int MOUT>
__device__ __forceinline__ void level_m(
    const _Float16* inb, _Float16* outb,
    const half8 (&Wf)[4][8], const float (&bias)[4],
    int m0, int nbase, int l15, int quad)
{
#pragma unroll
  for (int m = 0; m < MTW; ++m) {
    const int gm = m0 + m;
    const _Float16* arow = inb + (gm * 16 + l15) * STRIDE + quad * 8;
    floatx4 acc[4];
#pragma unroll
    for (int i = 0; i < 4; ++i) acc[i] = (floatx4){0.f, 0.f, 0.f, 0.f};
#pragma unroll
    for (int ks = 0; ks < 8; ++ks) {
      half8 a = *(const half8*)(arow + ks * 32);
#pragma unroll
      for (int i = 0; i < 4; ++i)
        acc[i] = __builtin_amdgcn_mfma_f32_16x16x32_f16(a, Wf[i][ks], acc[i], 0, 0, 0);
    }
    const int mrow = quad * 4;
#pragma unroll
    for (int i = 0; i < 4; ++i) {
      const int col = (nbase + i) * 16 + l15;
#pragma unroll
      for (int r = 0; r < 4; ++r) {
        const int node = gm * 16 + mrow + r;
        if (node < MOUT) {
          float v = fast_tanh(acc[i][r] + bias[i]);
          outb[(node >> 1) * STRIDE + (node & 1) * 128 + col] = (_Float16)v;
        }
      }
    }
  }
}

// Deep level (1 m-tile): this wave computes its 2 deep n-tiles (local Wf index d0, d0+1).
// K-split into 2 independent 4-chains x 2 n = 4 chains. RCLAMP: max valid input row.
template<int MOUT, int RCLAMP>
__device__ __forceinline__ void level_deep(
    const _Float16* inb, _Float16* outb,
    const half8 (&Wf)[4][8], const float (&bias)[4],
    int d0, int nbase, int l15, int quad)
{
  const int rr = l15 < RCLAMP ? l15 : RCLAMP;
  const _Float16* arow = inb + rr * STRIDE + quad * 8;
  floatx4 aA[2], aB[2];
  aA[0] = (floatx4){0.f, 0.f, 0.f, 0.f}; aA[1] = (floatx4){0.f, 0.f, 0.f, 0.f};
  aB[0] = (floatx4){0.f, 0.f, 0.f, 0.f}; aB[1] = (floatx4){0.f, 0.f, 0.f, 0.f};
#pragma unroll
  for (int ks = 0; ks < 4; ++ks) {
    half8 x0 = *(const half8*)(arow + ks * 32);
    half8 x1 = *(const half8*)(arow + (ks + 4) * 32);
    aA[0] = __builtin_amdgcn_mfma_f32_16x16x32_f16(x0, Wf[d0][ks],         aA[0], 0, 0, 0);
    aB[0] = __builtin_amdgcn_mfma_f32_16x16x32_f16(x1, Wf[d0][ks + 4],     aB[0], 0, 0, 0);
    aA[1] = __builtin_amdgcn_mfma_f32_16x16x32_f16(x0, Wf[d0 + 1][ks],     aA[1], 0, 0, 0);
    aB[1] = __builtin_amdgcn_mfma_f32_16x16x32_f16(x1, Wf[d0 + 1][ks + 4], aB[1], 0, 0, 0);
  }
  const int mrow = quad * 4;
#pragma unroll
  for (int i = 0; i < 2; ++i) {
    floatx4 acc = aA[i] + aB[i];
    const int col = (nbase + d0 + i) * 16 + l15;
    const float b = bias[d0 + i];
#pragma unroll
    for (int r = 0; r < 4; ++r) {
      const int node = mrow + r;
      if (node < MOUT) {
        float v = fast_tanh(acc[r] + b);
        outb[(node >> 1) * STRIDE + (node & 1) * 128 + col] = (_Float16)v;
      }
    }
  }
}

__global__ __launch_bounds__(256, 1)   // cap 256 VGPR (allocator targets 2 waves/EU)
void tree_kernel(const int* __restrict__ tokens,
                 const float* __restrict__ embedding,
                 const float* __restrict__ W_tree,
                 const float* __restrict__ b_tree,
                 const float* __restrict__ W_cls,
                 const float* __restrict__ b_cls,
                 float* __restrict__ out)
{
  __shared__ __align__(16) _Float16 bufA[64 * STRIDE];   // leaves / even outputs (33.8 KB)
  __shared__ __align__(16) _Float16 bufB[32 * STRIDE];   // odd outputs (16.9 KB)
  __shared__ __align__(16) _Float16 bufC[4 * STRIDE];    // pair stash: L4 outs (2.1 KB)
  __shared__ float wavepart[4][2][3];                    // classifier partials (96 B)

  const int tid  = threadIdx.x;
  const int wid  = tid >> 6;
  const int lane = tid & 63;
  const int l15  = lane & 15;
  const int quad = lane >> 4;
  const int nbase = (wid & 1) * 4;         // wave's n-tile base: features [64*(wid&1), +64)
  const int mhalf = wid >> 1;              // m-split half for L0/L1
  const int d0    = mhalf * 2;             // deep levels: local Wf tile index {0 or 2}
  const int row  = tid & 63;               // gather destination row
  const int seg  = tid >> 6;               // gather leaf-half / feature-half segment
  const int tidx = 2 * row + (seg >> 1);   // this thread's token index within a sample

  // ---- stage this wave's 4 n-tiles of W_tree as B-fragments (128 VGPR) ----
  // B[k][n] = W_tree[e=n][h=k]  (einsum 'bnh,eh->bne' => out = comb @ W^T)
  half8 Wf[4][8];
#pragma unroll
  for (int i = 0; i < 4; ++i) {
    const int e = (nbase + i) * 16 + l15;
#pragma unroll
    for (int ks = 0; ks < 8; ++ks) {
      const int k = ks * 32 + quad * 8;
      const float4* p = (const float4*)(W_tree + e * 256 + k);
      float4 lo = p[0], hi = p[1];
      half8 f;
      f[0] = (_Float16)lo.x; f[1] = (_Float16)lo.y; f[2] = (_Float16)lo.z; f[3] = (_Float16)lo.w;
      f[4] = (_Float16)hi.x; f[5] = (_Float16)hi.y; f[6] = (_Float16)hi.z; f[7] = (_Float16)hi.w;
      Wf[i][ks] = f;
    }
  }
  float bias[4];
#pragma unroll
  for (int i = 0; i < 4; ++i) bias[i] = b_tree[(nbase + i) * 16 + l15];

  // classifier weights for this lane's 4 columns (12 VGPR; deep tiles use [d0],[d0+1])
  float wc[4][3];
#pragma unroll
  for (int i = 0; i < 4; ++i) {
    const int col = (nbase + i) * 16 + l15;
#pragma unroll
    for (int o = 0; o < 3; ++o) wc[i][o] = W_cls[o * 128 + col];
  }

  int tokA = tokens[(2 * blockIdx.x) * 128 + tidx];   // preloaded s0 token (first pair)

#pragma unroll 1
  for (int p = blockIdx.x; p < NPAIR; p += gridDim.x) {
    int pn = p + gridDim.x;
    if (pn >= NPAIR) pn = p;               // last iteration: harmless self-reload

    // ================= s0 =================
    gather_leafhalf(tokA, embedding, bufA, row, seg);
    const int tokB = tokens[(2 * p + 1) * 128 + tidx];
    __syncthreads();
    level_m<2, 64>(bufA, bufB, Wf, bias, mhalf * 2, nbase, l15, quad);    // L0 (m-split)
    __syncthreads();
    level_m<1, 32>(bufB, bufA, Wf, bias, mhalf,     nbase, l15, quad);    // L1 (m-split)
    __syncthreads();
    level_deep<16, 15>(bufA, bufB, Wf, bias, d0, nbase, l15, quad);       // L2 (n-split)
    __syncthreads();
    level_deep< 8,  7>(bufB, bufA, Wf, bias, d0, nbase, l15, quad);       // L3
    __syncthreads();
    level_deep< 4,  3>(bufA, bufC, Wf, bias, d0, nbase, l15, quad);       // L4 -> bufC 0-1
    __syncthreads();

    // ================= s1 =================
    gather_leafhalf(tokB, embedding, bufA, row, seg);
    tokA = tokens[(2 * pn) * 128 + tidx];
    __syncthreads();
    level_m<2, 64>(bufA, bufB, Wf, bias, mhalf * 2, nbase, l15, quad);    // L0
    __syncthreads();
    level_m<1, 32>(bufB, bufA, Wf, bias, mhalf,     nbase, l15, quad);    // L1
    __syncthreads();
    level_deep<16, 15>(bufA, bufB, Wf, bias, d0, nbase, l15, quad);       // L2
    __syncthreads();
    level_deep< 8,  7>(bufB, bufA, Wf, bias, d0, nbase, l15, quad);       // L3
    __syncthreads();
    level_deep< 4,  3>(bufA, bufC + 2 * STRIDE, Wf, bias, d0, nbase, l15, quad); // L4 -> 2-3
    __syncthreads();

    // ---- batched L5: bufC rows 0-3 (pair) -> bufA rows 0-1 ----
    level_deep<4, 3>(bufC, bufA, Wf, bias, d0, nbase, l15, quad);
    __syncthreads();

    // ---- batched L6 + classifier partials from registers ----
    {
      const int rr = l15 < 1 ? l15 : 1;              // rows 0-1 valid = roots s0,s1
      const _Float16* arow = bufA + rr * STRIDE + quad * 8;
      floatx4 aA[2], aB[2];
      aA[0] = (floatx4){0.f, 0.f, 0.f, 0.f}; aA[1] = (floatx4){0.f, 0.f, 0.f, 0.f};
      aB[0] = (floatx4){0.f, 0.f, 0.f, 0.f}; aB[1] = (floatx4){0.f, 0.f, 0.f, 0.f};
#pragma unroll
      for (int ks = 0; ks < 4; ++ks) {
        half8 x0 = *(const half8*)(arow + ks * 32);
        half8 x1 = *(const half8*)(arow + (ks + 4) * 32);
        aA[0] = __builtin_amdgcn_mfma_f32_16x16x32_f16(x0, Wf[d0][ks],         aA[0], 0, 0, 0);
        aB[0] = __builtin_amdgcn_mfma_f32_16x16x32_f16(x1, Wf[d0][ks + 4],     aB[0], 0, 0, 0);
        aA[1] = __builtin_amdgcn_mfma_f32_16x16x32_f16(x0, Wf[d0 + 1][ks],     aA[1], 0, 0, 0);
        aB[1] = __builtin_amdgcn_mfma_f32_16x16x32_f16(x1, Wf[d0 + 1][ks + 4], aB[1], 0, 0, 0);
      }
      float part[2][3] = {{0.f, 0.f, 0.f}, {0.f, 0.f, 0.f}};
      if (quad == 0) {
#pragma unroll
        for (int i = 0; i < 2; ++i) {
          floatx4 acc = aA[i] + aB[i];
#pragma unroll
          for (int s = 0; s < 2; ++s) {              // s = sample (row 0/1 = reg 0/1)
            float v = fast_tanh(acc[s] + bias[d0 + i]);
#pragma unroll
            for (int o = 0; o < 3; ++o) part[s][o] = fmaf(v, wc[d0 + i][o], part[s][o]);
          }
        }
      }
#pragma unroll
      for (int s = 0; s < 2; ++s) {
#pragma unroll
        for (int o = 0; o < 3; ++o) {
          float v = part[s][o];                      // nonzero only in quad-0 lanes
          v += __shfl_down(v, 8);
          v += __shfl_down(v, 4);
          v += __shfl_down(v, 2);
          v += __shfl_down(v, 1);
          if (lane == 0) wavepart[wid][s][o] = v;
        }
      }
    }
    __syncthreads();
    if (tid < 6) {
      const int s = tid / 3, o = tid - 3 * s;
      float v = wavepart[0][s][o] + wavepart[1][s][o]
              + wavepart[2][s][o] + wavepart[3][s][o];
      out[(2 * p + s) * 3 + o] = v + b_cls[o];
    }
    // next pair's gather overwrites bufA: all L6 bufA reads completed before the wavepart
    // barrier; wavepart next written many barriers later -> safe.
  }
}

extern "C" void kernel_launch(void* const* d_in, const int* in_sizes, int n_in,
                              void* d_out, int out_size, void* d_ws, size_t ws_size,
                              hipStream_t stream) {
  const int*   tokens    = (const int*)d_in[0];
  const float* embedding = (const float*)d_in[1];
  const float* W_tree    = (const float*)d_in[2];
  const float* b_tree    = (const float*)d_in[3];
  const float* W_cls     = (const float*)d_in[4];
  const float* b_cls     = (const float*)d_in[5];
  float* out = (float*)d_out;

  dim3 grid(512), block(256);   // 2 blocks/CU (VGPR-bound); grid-stride over 2048 pairs
  tree_kernel<<<grid, block, 0, stream>>>(tokens, embedding, W_tree, b_tree, W_cls, b_cls, out);
}

// Round 16
// 167.044 us; speedup vs baseline: 1.7394x; 1.7394x over previous
//
#include <hip/hip_runtime.h>
#include <hip/hip_fp16.h>

// Tree NN: reps = emb[tokens] (4096 x 128 x 128); 7x: reps = tanh(concat(pairs) @ W_tree^T + b);
// out = root @ W_cls^T + b_cls.
//
// R16 = R13 (best) + gather sections folded into L3/L4. R15 confirmed the allocator never
// grants >~80 VGPR of long-lived state (Wf stays 2 n-tiles/wave); corrected audit shows no
// pipe >35% busy -- the wall is 14 barrier-serialized sections/pair. Choreography change:
// L3 writes bufB rows 8-11 (was bufA 0-3), L4 reads bufB 8-11 -> bufA is dead from after
// L2 until next L0, so the NEXT sample's gather runs inside L3 (chunks 0-3) and L4
// (chunks 4-7) sections: 14 -> 12 sections/pair and ~1.6k cyc/pair of exposed gather
// latency overlapped with MFMA. Tokens preloaded one sample early at L0 (1 VGPR).
// L5 -> bufB rows 0-1 (dead); L6 reads bufB. No state held across barriers beyond R13.
// Tripwire: WRITE_SIZE in MBs = in-section gather spilled past cap 80 -> revert to R13.
//
// Wave w owns output n-tiles {2w,2w+1} at every level (Wf[2][8] = 64 VGPR of W-fragments).
// Pair-contiguous LDS layout (concat free); conflict-reduced gather writes (R12);
// stale-row read clamps (R14, neutral-but-free). fp16 MFMA 16x16x32 (K-split 2x4 chains),
// fp32 accumulate/tanh/classifier.

typedef _Float16 half8 __attribute__((ext_vector_type(8)));
typedef float floatx4 __attribute__((ext_vector_type(4)));

#define STRIDE 264   // 256 + 8 fp16 pad: A-row ds_read_b128 conflict-free
#define UROW   33    // uint4 per row
#define NPAIR  2048

__device__ __forceinline__ float fast_tanh(float x) {
  // No clamp needed: e=inf -> 1; e=0 -> -1. Inputs never NaN.
  float e = __expf(2.f * x);
  return 1.f - 2.f * __builtin_amdgcn_rcpf(e + 1.f);
}

__device__ __forceinline__ unsigned pkrtz(float a, float b) {
  auto h = __builtin_amdgcn_cvt_pkrtz(a, b);   // __fp16 ext_vector(2)
  return __builtin_bit_cast(unsigned, h);
}

// Gather: thread (row=t&63, seg=t>>6) covers leaf 2*row+(seg>>1), feature-half seg&1.
// Writes uint4 j in [J0,J1) at row*33+seg*8+j; 8 consecutive lanes hit 8 consecutive
// rows -> conflict-free phases. Chunks split across sections (J0..J1).
template<int J0, int J1>
__device__ __forceinline__ void gather_chunk(int tok, const float* __restrict__ emb,
                                             _Float16* buf, int row, int seg) {
  const float4* src = (const float4*)emb + (size_t)tok * 32 + (seg & 1) * 16;
  uint4* dst = (uint4*)buf + row * UROW + seg * 8;
#pragma unroll
  for (int j = J0; j < J1; ++j) {
    float4 x = src[2 * j], y = src[2 * j + 1];
    uint4 w;
    w.x = pkrtz(x.x, x.y); w.y = pkrtz(x.z, x.w);
    w.z = pkrtz(y.x, y.y); w.w = pkrtz(y.z, y.w);
    dst[j] = w;
  }
}

// K=256 MFMA for one 16-row m-tile, 2 n-tiles, K-split into 2 independent 4-chains.
// A-frag: A[m=lane&15][k=quad*8+j]; B-frag: B[k=quad*8+j][n=lane&15];
// D: col=lane&15, row=quad*4+reg (verified layouts, learn_hip m89/m91).
__device__ __forceinline__ void mfma_k256(const _Float16* arow, const half8 (&Wf)[2][8],
                                          floatx4 (&accO)[2]) {
  floatx4 aA[2], aB[2];
  aA[0] = (floatx4){0.f, 0.f, 0.f, 0.f}; aA[1] = (floatx4){0.f, 0.f, 0.f, 0.f};
  aB[0] = (floatx4){0.f, 0.f, 0.f, 0.f}; aB[1] = (floatx4){0.f, 0.f, 0.f, 0.f};
#pragma unroll
  for (int ks = 0; ks < 4; ++ks) {
    half8 x0 = *(const half8*)(arow + ks * 32);
    half8 x1 = *(const half8*)(arow + (ks + 4) * 32);
    aA[0] = __builtin_amdgcn_mfma_f32_16x16x32_f16(x0, Wf[0][ks],     aA[0], 0, 0, 0);
    aB[0] = __builtin_amdgcn_mfma_f32_16x16x32_f16(x1, Wf[0][ks + 4], aB[0], 0, 0, 0);
    aA[1] = __builtin_amdgcn_mfma_f32_16x16x32_f16(x0, Wf[1][ks],     aA[1], 0, 0, 0);
    aB[1] = __builtin_amdgcn_mfma_f32_16x16x32_f16(x1, Wf[1][ks + 4], aB[1], 0, 0, 0);
  }
  accO[0] = aA[0] + aB[0];
  accO[1] = aA[1] + aB[1];
}

// One wave: its 2 n-tiles for MT m-tiles; store row = (node>>1) relative to outb,
// half (node&1). RCLAMP (<15): max valid input row at MT=1 (excess lanes broadcast).
// In/out pointers carry any row offsets (e.g. L3 out = bufB + 8*STRIDE).
template<int MT, int MOUT, int RCLAMP>
__device__ __forceinline__ void level_std(
    const _Float16* inb, _Float16* outb,
    const half8 (&Wf)[2][8], const float (&bias)[2],
    int nbase, int l15, int quad)
{
  floatx4 acc[MT][2];
  if (MT == 1) {
    const int rr = (RCLAMP < 15) ? (l15 < RCLAMP ? l15 : RCLAMP) : l15;
    floatx4 a2[2];
    mfma_k256(inb + rr * STRIDE + quad * 8, Wf, a2);
    acc[0][0] = a2[0]; acc[0][1] = a2[1];
  } else {
#pragma unroll
    for (int m = 0; m < MT; ++m) {
      acc[m][0] = (floatx4){0.f, 0.f, 0.f, 0.f};
      acc[m][1] = (floatx4){0.f, 0.f, 0.f, 0.f};
    }
#pragma unroll
    for (int m = 0; m < MT; ++m) {
      const _Float16* arow = inb + (m * 16 + l15) * STRIDE + quad * 8;
#pragma unroll
      for (int ks = 0; ks < 8; ++ks) {
        half8 a = *(const half8*)(arow + ks * 32);
        acc[m][0] = __builtin_amdgcn_mfma_f32_16x16x32_f16(a, Wf[0][ks], acc[m][0], 0, 0, 0);
        acc[m][1] = __builtin_amdgcn_mfma_f32_16x16x32_f16(a, Wf[1][ks], acc[m][1], 0, 0, 0);
      }
    }
  }

  const int mrow = quad * 4;
#pragma unroll
  for (int m = 0; m < MT; ++m)
#pragma unroll
    for (int i = 0; i < 2; ++i) {
      const int col = (nbase + i) * 16 + l15;
#pragma unroll
      for (int r = 0; r < 4; ++r) {
        const int node = m * 16 + mrow + r;
        if (node < MOUT) {
          float v = fast_tanh(acc[m][i][r] + bias[i]);
          outb[(node >> 1) * STRIDE + (node & 1) * 128 + col] = (_Float16)v;
        }
      }
    }
}

__global__ __launch_bounds__(256, 3)   // proven config: cap 80, 3 blocks/CU
void tree_kernel(const int* __restrict__ tokens,
                 const float* __restrict__ embedding,
                 const float* __restrict__ W_tree,
                 const float* __restrict__ b_tree,
                 const float* __restrict__ W_cls,
                 const float* __restrict__ b_cls,
                 float* __restrict__ out)
{
  __shared__ __align__(16) _Float16 bufA[64 * STRIDE];   // leaves + L1-out rows 0-15 (33.8 KB)
  __shared__ __align__(16) _Float16 bufB[32 * STRIDE];   // L0/L2/L3/L5-outs (16.9 KB)
  __shared__ __align__(16) _Float16 bufC[4 * STRIDE];    // pair stash: L4 outs (2.1 KB)
  __shared__ float wavepart[4][2][3];                    // classifier partials (96 B)

  const int tid  = threadIdx.x;
  const int wid  = tid >> 6;
  const int lane = tid & 63;
  const int l15  = lane & 15;
  const int quad = lane >> 4;
  const int nbase = wid * 2;               // this wave's n-tile base (features [32*wid,32*wid+32))
  const int row  = tid & 63;               // gather destination row
  const int seg  = tid >> 6;               // gather leaf-half / feature-half segment
  const int tidx = 2 * row + (seg >> 1);   // this thread's token index within a sample

  // ---- stage this wave's 2 n-tiles of W_tree as B-fragments (64 VGPR) ----
  // B[k][n] = W_tree[e=n][h=k]  (einsum 'bnh,eh->bne' => out = comb @ W^T)
  half8 Wf[2][8];
#pragma unroll
  for (int i = 0; i < 2; ++i) {
    const int e = (nbase + i) * 16 + l15;
#pragma unroll
    for (int ks = 0; ks < 8; ++ks) {
      const int k = ks * 32 + quad * 8;
      const float4* p = (const float4*)(W_tree + e * 256 + k);
      float4 lo = p[0], hi = p[1];
      half8 f;
      f[0] = (_Float16)lo.x; f[1] = (_Float16)lo.y; f[2] = (_Float16)lo.z; f[3] = (_Float16)lo.w;
      f[4] = (_Float16)hi.x; f[5] = (_Float16)hi.y; f[6] = (_Float16)hi.z; f[7] = (_Float16)hi.w;
      Wf[i][ks] = f;
    }
  }
  float bias[2];
#pragma unroll
  for (int i = 0; i < 2; ++i) bias[i] = b_tree[(nbase + i) * 16 + l15];

  // classifier weights for this lane's 2 columns: loop-invariant (6 VGPR)
  float wc[2][3];
#pragma unroll
  for (int i = 0; i < 2; ++i) {
    const int col = (nbase + i) * 16 + l15;
#pragma unroll
    for (int o = 0; o < 3; ++o) wc[i][o] = W_cls[o * 128 + col];
  }

  // ---- prologue: gather first pair's s0 into bufA (its own section, once) ----
  {
    const int tok = tokens[(2 * blockIdx.x) * 128 + tidx];
    gather_chunk<0, 8>(tok, embedding, bufA, row, seg);
  }
  __syncthreads();

#pragma unroll 1
  for (int p = blockIdx.x; p < NPAIR; p += gridDim.x) {
    int pn = p + gridDim.x;
    if (pn >= NPAIR) pn = p;               // last iteration: harmless self-reload

    // ===== s0 ===== (leaves already in bufA)
    // L0: bufA 0-63 -> bufB 0-31; preload s1 token (1 VGPR, used in L3/L4)
    level_std<4, 64, 15>(bufA, bufB, Wf, bias, nbase, l15, quad);
    const int tokB = tokens[(2 * p + 1) * 128 + tidx];
    __syncthreads();
    // L1: bufB 0-31 -> bufA 0-15 (leaf rows dead after L0)
    level_std<2, 32, 15>(bufB, bufA, Wf, bias, nbase, l15, quad);
    __syncthreads();
    // L2: bufA 0-15 -> bufB 0-7
    level_std<1, 16, 15>(bufA, bufB, Wf, bias, nbase, l15, quad);
    __syncthreads();
    // L3: bufB 0-7 -> bufB 8-11 (disjoint rows); bufA fully dead -> gather s1 chunks 0-3
    gather_chunk<0, 4>(tokB, embedding, bufA, row, seg);
    level_std<1, 8, 7>(bufB, bufB + 8 * STRIDE, Wf, bias, nbase, l15, quad);
    __syncthreads();
    // L4: bufB 8-11 -> bufC 0-1; gather s1 chunks 4-7
    gather_chunk<4, 8>(tokB, embedding, bufA, row, seg);
    level_std<1, 4, 3>(bufB + 8 * STRIDE, bufC, Wf, bias, nbase, l15, quad);
    __syncthreads();

    // ===== s1 ===== (leaves in bufA)
    // L0; preload next-pair s0 token (used in L3/L4 below)
    level_std<4, 64, 15>(bufA, bufB, Wf, bias, nbase, l15, quad);
    const int tokA2 = tokens[(2 * pn) * 128 + tidx];
    __syncthreads();
    level_std<2, 32, 15>(bufB, bufA, Wf, bias, nbase, l15, quad);
    __syncthreads();
    level_std<1, 16, 15>(bufA, bufB, Wf, bias, nbase, l15, quad);
    __syncthreads();
    gather_chunk<0, 4>(tokA2, embedding, bufA, row, seg);   // next-pair s0, chunks 0-3
    level_std<1, 8, 7>(bufB, bufB + 8 * STRIDE, Wf, bias, nbase, l15, quad);
    __syncthreads();
    gather_chunk<4, 8>(tokA2, embedding, bufA, row, seg);   // chunks 4-7
    level_std<1, 4, 3>(bufB + 8 * STRIDE, bufC + 2 * STRIDE, Wf, bias, nbase, l15, quad);
    __syncthreads();

    // ---- batched L5: bufC rows 0-3 -> bufB rows 0-1 (all bufB rows dead) ----
    {
      const int rclamp = l15 < 4 ? l15 : 3;          // bufC bounds; rows>=4 discarded
      floatx4 acc[2];
      mfma_k256(bufC + rclamp * STRIDE + quad * 8, Wf, acc);
      const int mrow = quad * 4;
#pragma unroll
      for (int i = 0; i < 2; ++i) {
        const int col = (nbase + i) * 16 + l15;
#pragma unroll
        for (int r = 0; r < 4; ++r) {
          const int mr = mrow + r;                   // mr<4 valid: sample mr>>1, node mr&1
          if (mr < 4) {
            float v = fast_tanh(acc[i][r] + bias[i]);
            bufB[(mr >> 1) * STRIDE + (mr & 1) * 128 + col] = (_Float16)v;
          }
        }
      }
    }
    __syncthreads();

    // ---- batched L6 + classifier partials from registers ----
    {
      const int rclamp = l15 < 2 ? l15 : 1;          // rows 0-1 valid = roots s0,s1
      floatx4 acc[2];
      mfma_k256(bufB + rclamp * STRIDE + quad * 8, Wf, acc);
      float part[2][3] = {{0.f, 0.f, 0.f}, {0.f, 0.f, 0.f}};
      if (quad == 0) {
#pragma unroll
        for (int i = 0; i < 2; ++i) {
#pragma unroll
          for (int rr = 0; rr < 2; ++rr) {           // rr = sample
            float v = fast_tanh(acc[i][rr] + bias[i]);
#pragma unroll
            for (int o = 0; o < 3; ++o) part[rr][o] = fmaf(v, wc[i][o], part[rr][o]);
          }
        }
      }
#pragma unroll
      for (int rr = 0; rr < 2; ++rr) {
#pragma unroll
        for (int o = 0; o < 3; ++o) {
          float v = part[rr][o];                     // nonzero only in quad-0 lanes
          v += __shfl_down(v, 8);
          v += __shfl_down(v, 4);
          v += __shfl_down(v, 2);
          v += __shfl_down(v, 1);
          if (lane == 0) wavepart[wid][rr][o] = v;
        }
      }
    }
    __syncthreads();
    if (tid < 6) {
      const int rr = tid / 3, o = tid - 3 * rr;
      float v = wavepart[0][rr][o] + wavepart[1][rr][o]
              + wavepart[2][rr][o] + wavepart[3][rr][o];
      out[(2 * p + rr) * 3 + o] = v + b_cls[o];
    }
    // loop: next L0 reads bufA (gathered during s1's L3/L4, >=2 barriers ago) and writes
    // bufB 0-31 (L6's bufB reads complete before the wavepart barrier) -> safe.
  }
}

extern "C" void kernel_launch(void* const* d_in, const int* in_sizes, int n_in,
                              void* d_out, int out_size, void* d_ws, size_t ws_size,
                              hipStream_t stream) {
  const int*   tokens    = (const int*)d_in[0];
  const float* embedding = (const float*)d_in[1];
  const float* W_tree    = (const float*)d_in[2];
  const float* b_tree    = (const float*)d_in[3];
  const float* W_cls     = (const float*)d_in[4];
  const float* b_cls     = (const float*)d_in[5];
  float* out = (float*)d_out;

  dim3 grid(768), block(256);   // 3 blocks/CU x 256 CUs; grid-stride over 2048 pairs
  tree_kernel<<<grid, block, 0, stream>>>(tokens, embedding, W_tree, b_tree, W_cls, b_cls, out);
}

// Round 17
// 156.798 us; speedup vs baseline: 1.8530x; 1.0653x over previous
//
#include <hip/hip_runtime.h>
#include <hip/hip_fp16.h>

// Tree NN: reps = emb[tokens] (4096 x 128 x 128); 7x: reps = tanh(concat(pairs) @ W_tree^T + b);
// out = root @ W_cls^T + b_cls.
//
// FINAL (R17) = R13, the best measured kernel (83.5us dispatch / 154.3us bench).
// Session findings baked into this structure:
//  - Wave w owns output n-tiles {2w,2w+1} at EVERY level: Wf[2][8] = 64 VGPR of
//    W-fragments is the most the allocator sustains without spilling (~80 VGPR cap at
//    3 blocks/CU; 4-tile Wf, cross-barrier prefetch, and in-section gathers all spilled:
//    R2/R5/R6/R15/R16).
//  - lb(256,3) is the only config delivering no-spill AND ~30% occupancy (R3 vs R2/R10/R15).
//  - Pair-batched deep tail (L5/L6 once per 2 samples) -- R9, -7us.
//  - K-split MFMA (2 independent 4-chains) halves the deep-level dependency path -- R8.
//  - Conflict-free gather writes (row t&63, seg t>>6): -3.15M conflict cycles -- R12/R13.
//  - Token preload one section early kills the token->embedding serial chain -- R13.
//  - Plateau cause: 14 barrier-serialized sections/pair, __syncthreads drains vmcnt(0);
//    no pipe >35% busy. Latency-structure-bound, not a hardware roofline.
// fp16 MFMA 16x16x32, fp32 accumulate/tanh/classifier. absmax 3.9e-3 (thr 2.1e-2).

typedef _Float16 half8 __attribute__((ext_vector_type(8)));
typedef float floatx4 __attribute__((ext_vector_type(4)));

#define STRIDE 264   // 256 + 8 fp16 pad: A-row ds_read_b128 conflict-free
#define UROW   33    // uint4 per row
#define NPAIR  2048

__device__ __forceinline__ float fast_tanh(float x) {
  // No clamp needed: e=inf -> 1; e=0 -> -1. Inputs never NaN.
  float e = __expf(2.f * x);
  return 1.f - 2.f * __builtin_amdgcn_rcpf(e + 1.f);
}

__device__ __forceinline__ unsigned pkrtz(float a, float b) {
  auto h = __builtin_amdgcn_cvt_pkrtz(a, b);   // __fp16 ext_vector(2)
  return __builtin_bit_cast(unsigned, h);
}

// Gather: thread (row=t&63, seg=t>>6) covers leaf 2*row+(seg>>1), feature-half seg&1.
// 8 consecutive lanes hit 8 consecutive rows -> distinct bank-quads -> conflict-free.
__device__ __forceinline__ void gather_leafhalf(int tok, const float* __restrict__ emb,
                                                _Float16* buf, int row, int seg) {
  const float4* src = (const float4*)emb + (size_t)tok * 32 + (seg & 1) * 16;
  uint4* dst = (uint4*)buf + row * UROW + seg * 8;
#pragma unroll
  for (int j = 0; j < 8; ++j) {
    float4 x = src[2 * j], y = src[2 * j + 1];
    uint4 w;
    w.x = pkrtz(x.x, x.y); w.y = pkrtz(x.z, x.w);
    w.z = pkrtz(y.x, y.y); w.w = pkrtz(y.z, y.w);
    dst[j] = w;
  }
}

// K=256 MFMA for one 16-row m-tile, 2 n-tiles, K-split into 2 independent 4-chains.
// A-frag: A[m=lane&15][k=quad*8+j]; B-frag: B[k=quad*8+j][n=lane&15];
// D: col=lane&15, row=quad*4+reg (verified layouts, learn_hip m89/m91).
__device__ __forceinline__ void mfma_k256(const _Float16* arow, const half8 (&Wf)[2][8],
                                          floatx4 (&accO)[2]) {
  floatx4 aA[2], aB[2];
  aA[0] = (floatx4){0.f, 0.f, 0.f, 0.f}; aA[1] = (floatx4){0.f, 0.f, 0.f, 0.f};
  aB[0] = (floatx4){0.f, 0.f, 0.f, 0.f}; aB[1] = (floatx4){0.f, 0.f, 0.f, 0.f};
#pragma unroll
  for (int ks = 0; ks < 4; ++ks) {
    half8 x0 = *(const half8*)(arow + ks * 32);
    half8 x1 = *(const half8*)(arow + (ks + 4) * 32);
    aA[0] = __builtin_amdgcn_mfma_f32_16x16x32_f16(x0, Wf[0][ks],     aA[0], 0, 0, 0);
    aB[0] = __builtin_amdgcn_mfma_f32_16x16x32_f16(x1, Wf[0][ks + 4], aB[0], 0, 0, 0);
    aA[1] = __builtin_amdgcn_mfma_f32_16x16x32_f16(x0, Wf[1][ks],     aA[1], 0, 0, 0);
    aB[1] = __builtin_amdgcn_mfma_f32_16x16x32_f16(x1, Wf[1][ks + 4], aB[1], 0, 0, 0);
  }
  accO[0] = aA[0] + aB[0];
  accO[1] = aA[1] + aB[1];
}

// One wave: its 2 n-tiles for MT m-tiles; pair-contiguous store, MOUT row mask.
// Stale rows above MOUT always hold finite tanh/leaf values; masked at store.
template<int MT, int MOUT>
__device__ __forceinline__ void level_std(
    const _Float16* inb, _Float16* outb,
    const half8 (&Wf)[2][8], const float (&bias)[2],
    int nbase, int l15, int quad)
{
  floatx4 acc[MT][2];
  if (MT == 1) {
    floatx4 a2[2];
    mfma_k256(inb + l15 * STRIDE + quad * 8, Wf, a2);
    acc[0][0] = a2[0]; acc[0][1] = a2[1];
  } else {
#pragma unroll
    for (int m = 0; m < MT; ++m) {
      acc[m][0] = (floatx4){0.f, 0.f, 0.f, 0.f};
      acc[m][1] = (floatx4){0.f, 0.f, 0.f, 0.f};
    }
#pragma unroll
    for (int m = 0; m < MT; ++m) {
      const _Float16* arow = inb + (m * 16 + l15) * STRIDE + quad * 8;
#pragma unroll
      for (int ks = 0; ks < 8; ++ks) {
        half8 a = *(const half8*)(arow + ks * 32);
        acc[m][0] = __builtin_amdgcn_mfma_f32_16x16x32_f16(a, Wf[0][ks], acc[m][0], 0, 0, 0);
        acc[m][1] = __builtin_amdgcn_mfma_f32_16x16x32_f16(a, Wf[1][ks], acc[m][1], 0, 0, 0);
      }
    }
  }

  const int mrow = quad * 4;
#pragma unroll
  for (int m = 0; m < MT; ++m)
#pragma unroll
    for (int i = 0; i < 2; ++i) {
      const int col = (nbase + i) * 16 + l15;
#pragma unroll
      for (int r = 0; r < 4; ++r) {
        const int node = m * 16 + mrow + r;
        if (node < MOUT) {
          float v = fast_tanh(acc[m][i][r] + bias[i]);
          outb[(node >> 1) * STRIDE + (node & 1) * 128 + col] = (_Float16)v;
        }
      }
    }
}

__global__ __launch_bounds__(256, 3)   // proven config: cap 80 >= demand ~76, 3 blocks/CU
void tree_kernel(const int* __restrict__ tokens,
                 const float* __restrict__ embedding,
                 const float* __restrict__ W_tree,
                 const float* __restrict__ b_tree,
                 const float* __restrict__ W_cls,
                 const float* __restrict__ b_cls,
                 float* __restrict__ out)
{
  __shared__ __align__(16) _Float16 bufA[64 * STRIDE];   // leaves / even outputs (33.8 KB)
  __shared__ __align__(16) _Float16 bufB[32 * STRIDE];   // odd outputs (16.9 KB)
  __shared__ __align__(16) _Float16 bufC[4 * STRIDE];    // pair stash: L4 outs (2.1 KB)
  __shared__ float wavepart[4][2][3];                    // classifier partials (96 B)

  const int tid  = threadIdx.x;
  const int wid  = tid >> 6;
  const int lane = tid & 63;
  const int l15  = lane & 15;
  const int quad = lane >> 4;
  const int nbase = wid * 2;               // this wave's n-tile base (features [32*wid,32*wid+32))
  const int row  = tid & 63;               // gather destination row
  const int seg  = tid >> 6;               // gather leaf-half / feature-half segment
  const int tidx = 2 * row + (seg >> 1);   // this thread's token index within a sample

  // ---- stage this wave's 2 n-tiles of W_tree as B-fragments (64 VGPR) ----
  // B[k][n] = W_tree[e=n][h=k]  (einsum 'bnh,eh->bne' => out = comb @ W^T)
  half8 Wf[2][8];
#pragma unroll
  for (int i = 0; i < 2; ++i) {
    const int e = (nbase + i) * 16 + l15;
#pragma unroll
    for (int ks = 0; ks < 8; ++ks) {
      const int k = ks * 32 + quad * 8;
      const float4* p = (const float4*)(W_tree + e * 256 + k);
      float4 lo = p[0], hi = p[1];
      half8 f;
      f[0] = (_Float16)lo.x; f[1] = (_Float16)lo.y; f[2] = (_Float16)lo.z; f[3] = (_Float16)lo.w;
      f[4] = (_Float16)hi.x; f[5] = (_Float16)hi.y; f[6] = (_Float16)hi.z; f[7] = (_Float16)hi.w;
      Wf[i][ks] = f;
    }
  }
  float bias[2];
#pragma unroll
  for (int i = 0; i < 2; ++i) bias[i] = b_tree[(nbase + i) * 16 + l15];

  // classifier weights for this lane's 2 columns: loop-invariant (6 VGPR)
  float wc[2][3];
#pragma unroll
  for (int i = 0; i < 2; ++i) {
    const int col = (nbase + i) * 16 + l15;
#pragma unroll
    for (int o = 0; o < 3; ++o) wc[i][o] = W_cls[o * 128 + col];
  }

  int tokA = tokens[(2 * blockIdx.x) * 128 + tidx];   // preloaded s0 token (first pair)

#pragma unroll 1
  for (int p = blockIdx.x; p < NPAIR; p += gridDim.x) {
    int pn = p + gridDim.x;
    if (pn >= NPAIR) pn = p;               // last iteration: harmless self-reload

    // ---- s0 gather (token preloaded) + preload s1 token ----
    gather_leafhalf(tokA, embedding, bufA, row, seg);
    const int tokB = tokens[(2 * p + 1) * 128 + tidx];
    __syncthreads();

    // ---- s0 levels: L0..L4, stash L4-out in bufC rows 0-1 ----
    level_std<4, 64>(bufA, bufB, Wf, bias, nbase, l15, quad);   // L0
    __syncthreads();
    level_std<2, 32>(bufB, bufA, Wf, bias, nbase, l15, quad);   // L1
    __syncthreads();
    level_std<1, 16>(bufA, bufB, Wf, bias, nbase, l15, quad);   // L2
    __syncthreads();
    level_std<1,  8>(bufB, bufA, Wf, bias, nbase, l15, quad);   // L3
    __syncthreads();
    level_std<1,  4>(bufA, bufC, Wf, bias, nbase, l15, quad);   // L4 -> bufC rows 0-1
    __syncthreads();

    // ---- s1 gather (token preloaded) + preload next-pair s0 token ----
    gather_leafhalf(tokB, embedding, bufA, row, seg);
    tokA = tokens[(2 * pn) * 128 + tidx];
    __syncthreads();

    // ---- s1 levels: L0..L4, stash L4-out in bufC rows 2-3 ----
    level_std<4, 64>(bufA, bufB, Wf, bias, nbase, l15, quad);   // L0
    __syncthreads();
    level_std<2, 32>(bufB, bufA, Wf, bias, nbase, l15, quad);   // L1
    __syncthreads();
    level_std<1, 16>(bufA, bufB, Wf, bias, nbase, l15, quad);   // L2
    __syncthreads();
    level_std<1,  8>(bufB, bufA, Wf, bias, nbase, l15, quad);   // L3
    __syncthreads();
    level_std<1,  4>(bufA, bufC + 2 * STRIDE, Wf, bias, nbase, l15, quad); // L4 -> rows 2-3
    __syncthreads();

    // ---- batched L5: bufC rows 0-3 -> bufA rows 0-1 ----
    {
      const int rclamp = l15 < 4 ? l15 : 3;          // bufC bounds; rows>=4 discarded
      floatx4 acc[2];
      mfma_k256(bufC + rclamp * STRIDE + quad * 8, Wf, acc);
      const int mrow = quad * 4;
#pragma unroll
      for (int i = 0; i < 2; ++i) {
        const int col = (nbase + i) * 16 + l15;
#pragma unroll
        for (int r = 0; r < 4; ++r) {
          const int mr = mrow + r;                   // mr<4 valid: sample mr>>1, node mr&1
          if (mr < 4) {
            float v = fast_tanh(acc[i][r] + bias[i]);
            bufA[(mr >> 1) * STRIDE + (mr & 1) * 128 + col] = (_Float16)v;
          }
        }
      }
    }
    __syncthreads();

    // ---- batched L6 + classifier partials from registers ----
    {
      floatx4 acc[2];
      mfma_k256(bufA + l15 * STRIDE + quad * 8, Wf, acc);  // rows 0-1 valid = roots s0,s1
      float part[2][3] = {{0.f, 0.f, 0.f}, {0.f, 0.f, 0.f}};
      if (quad == 0) {
#pragma unroll
        for (int i = 0; i < 2; ++i) {
#pragma unroll
          for (int rr = 0; rr < 2; ++rr) {           // rr = sample
            float v = fast_tanh(acc[i][rr] + bias[i]);
#pragma unroll
            for (int o = 0; o < 3; ++o) part[rr][o] = fmaf(v, wc[i][o], part[rr][o]);
          }
        }
      }
#pragma unroll
      for (int rr = 0; rr < 2; ++rr) {
#pragma unroll
        for (int o = 0; o < 3; ++o) {
          float v = part[rr][o];                     // nonzero only in quad-0 lanes
          v += __shfl_down(v, 8);
          v += __shfl_down(v, 4);
          v += __shfl_down(v, 2);
          v += __shfl_down(v, 1);
          if (lane == 0) wavepart[wid][rr][o] = v;
        }
      }
    }
    __syncthreads();
    if (tid < 6) {
      const int rr = tid / 3, o = tid - 3 * rr;
      float v = wavepart[0][rr][o] + wavepart[1][rr][o]
              + wavepart[2][rr][o] + wavepart[3][rr][o];
      out[(2 * p + rr) * 3 + o] = v + b_cls[o];
    }
    // next pair's gather overwrites bufA: all L6 bufA reads completed before the wavepart
    // barrier; wavepart next written 13 barriers later -> safe.
  }
}

extern "C" void kernel_launch(void* const* d_in, const int* in_sizes, int n_in,
                              void* d_out, int out_size, void* d_ws, size_t ws_size,
                              hipStream_t stream) {
  const int*   tokens    = (const int*)d_in[0];
  const float* embedding = (const float*)d_in[1];
  const float* W_tree    = (const float*)d_in[2];
  const float* b_tree    = (const float*)d_in[3];
  const float* W_cls     = (const float*)d_in[4];
  const float* b_cls     = (const float*)d_in[5];
  float* out = (float*)d_out;

  dim3 grid(768), block(256);   // 3 blocks/CU x 256 CUs; grid-stride over 2048 pairs
  tree_kernel<<<grid, block, 0, stream>>>(tokens, embedding, W_tree, b_tree, W_cls, b_cls, out);
}